// Round 3
// baseline (2202.298 us; speedup 1.0000x reference)
//
#include <hip/hip_runtime.h>

// Fused: reshape -> (x @ w2) -> roll(H,+1) -> 7-tap H-conv (pad 3) with w1 -> roll(W,+1)
//
// out[b, c*12+i, h, wo], source column ws=(wo-1)%112 (W-roll folded into read).
// padded row p valid for 3<=p<=114 reads x row ht=(p-4) mod 112 (H-roll folded).
//
// ALL per-thread state is named scalars (no arrays) -> guaranteed VGPR, no
// scratch. Rolling 7x9 window of (x . w2) rows; weights in LDS (uniform
// broadcast ds_read_b128); raw-x prefetch issued before the 756-FMA conv so
// HBM latency hides under compute.

#define CHK 14   // h rows per thread
#define NCHK 8   // 112 / CHK

// ---- 9-wide window row K as named scalars ----
#define DECL_ROW(K) float w##K##_0, w##K##_1, w##K##_2, w##K##_3, w##K##_4, \
                          w##K##_5, w##K##_6, w##K##_7, w##K##_8
#define ZERO_ROW(K) w##K##_0=0.f; w##K##_1=0.f; w##K##_2=0.f; w##K##_3=0.f; \
                    w##K##_4=0.f; w##K##_5=0.f; w##K##_6=0.f; w##K##_7=0.f; w##K##_8=0.f
#define COPY_ROW(D,S) w##D##_0=w##S##_0; w##D##_1=w##S##_1; w##D##_2=w##S##_2; \
                      w##D##_3=w##S##_3; w##D##_4=w##S##_4; w##D##_5=w##S##_5; \
                      w##D##_6=w##S##_6; w##D##_7=w##S##_7; w##D##_8=w##S##_8

// ---- load 12 raw x values (px0..px11) for row HT, declaring consts ----
#define LOADPX(HT) \
    const size_t ro_ = (size_t)(HT) * 112; \
    const float px0  = xcol[ro_]; \
    const float px1  = xcol[ro_ +  1*12544]; \
    const float px2  = xcol[ro_ +  2*12544]; \
    const float px3  = xcol[ro_ +  3*12544]; \
    const float px4  = xcol[ro_ +  4*12544]; \
    const float px5  = xcol[ro_ +  5*12544]; \
    const float px6  = xcol[ro_ +  6*12544]; \
    const float px7  = xcol[ro_ +  7*12544]; \
    const float px8  = xcol[ro_ +  8*12544]; \
    const float px9  = xcol[ro_ +  9*12544]; \
    const float px10 = xcol[ro_ + 10*12544]; \
    const float px11 = xcol[ro_ + 11*12544]

// ---- t4 mix: window[j] = sum_ch px_ch * w2L[j*12+ch] ----
#define MIXJ(J) fmaf(px11, w2L[(J)*12+11], fmaf(px10, w2L[(J)*12+10], \
    fmaf(px9, w2L[(J)*12+9], fmaf(px8, w2L[(J)*12+8], fmaf(px7, w2L[(J)*12+7], \
    fmaf(px6, w2L[(J)*12+6], fmaf(px5, w2L[(J)*12+5], fmaf(px4, w2L[(J)*12+4], \
    fmaf(px3, w2L[(J)*12+3], fmaf(px2, w2L[(J)*12+2], fmaf(px1, w2L[(J)*12+1], \
    px0 * w2L[(J)*12+0])))))))))))
#define MIX_ROW(K) \
    w##K##_0 = MIXJ(0); w##K##_1 = MIXJ(1); w##K##_2 = MIXJ(2); \
    w##K##_3 = MIXJ(3); w##K##_4 = MIXJ(4); w##K##_5 = MIXJ(5); \
    w##K##_6 = MIXJ(6); w##K##_7 = MIXJ(7); w##K##_8 = MIXJ(8)

// ---- prologue slot fill: padded row p = h0 + K ----
#define FILL_SLOT(K) { \
    const int p_r = h0 + (K); \
    if (p_r < 3) { ZERO_ROW(K); } \
    else { int ht_ = p_r - 4; if (ht_ < 0) ht_ += 112; \
           LOADPX(ht_); MIX_ROW(K); } }

// ---- conv tap: acc_i += window_val * w1L[(K*9+J)*12 + i] ----
#define TAP(K,J,P) { const float p_ = (P); \
    const float* wl_ = &w1L[((K)*9+(J))*12]; \
    a0  = fmaf(p_, wl_[0],  a0 ); a1  = fmaf(p_, wl_[1],  a1 ); \
    a2  = fmaf(p_, wl_[2],  a2 ); a3  = fmaf(p_, wl_[3],  a3 ); \
    a4  = fmaf(p_, wl_[4],  a4 ); a5  = fmaf(p_, wl_[5],  a5 ); \
    a6  = fmaf(p_, wl_[6],  a6 ); a7  = fmaf(p_, wl_[7],  a7 ); \
    a8  = fmaf(p_, wl_[8],  a8 ); a9  = fmaf(p_, wl_[9],  a9 ); \
    a10 = fmaf(p_, wl_[10], a10); a11 = fmaf(p_, wl_[11], a11); }
#define TAPROW(K) \
    TAP(K,0,w##K##_0) TAP(K,1,w##K##_1) TAP(K,2,w##K##_2) \
    TAP(K,3,w##K##_3) TAP(K,4,w##K##_4) TAP(K,5,w##K##_5) \
    TAP(K,6,w##K##_6) TAP(K,7,w##K##_7) TAP(K,8,w##K##_8)

__global__ __launch_bounds__(128, 2)
void fused_shift_conv_kernel(const float* __restrict__ x,
                             const float* __restrict__ w1,   // (12,7,9)
                             const float* __restrict__ w2,   // (12,9)
                             float* __restrict__ out)
{
    __shared__ float w1L[756];   // [(k*9+j)*12 + i]
    __shared__ float w2L[108];   // [j*12 + ch]

    for (int idx = threadIdx.x; idx < 756; idx += 128) {
        int i  = idx / 63;
        int kj = idx - i * 63;
        w1L[kj * 12 + i] = w1[idx];
    }
    for (int idx = threadIdx.x; idx < 108; idx += 128) {
        int ch = idx / 9;
        int j  = idx - ch * 9;
        w2L[j * 12 + ch] = w2[idx];
    }
    __syncthreads();

    const int wo = threadIdx.x;                 // output column (aligned stores)
    if (wo >= 112) return;
    const int ws = (wo == 0) ? 111 : wo - 1;    // source column (W-roll on read)

    const int bid = blockIdx.x;
    const int hc  = bid & (NCHK - 1);
    const int c   = (bid >> 3) & 1;
    const int b   = bid >> 4;
    const int h0  = hc * CHK;

    const size_t slab = (size_t)(b * 24 + c * 12) * 12544;
    const float* xcol = x + slab + ws;
    float* ocol = out + slab + wo;

    DECL_ROW(0); DECL_ROW(1); DECL_ROW(2); DECL_ROW(3);
    DECL_ROW(4); DECL_ROW(5); DECL_ROW(6);

    // ---- prologue: padded rows h0 .. h0+6 ----
    FILL_SLOT(0) FILL_SLOT(1) FILL_SLOT(2) FILL_SLOT(3)
    FILL_SLOT(4) FILL_SLOT(5) FILL_SLOT(6)

    const int hend = h0 + CHK;
    #pragma unroll 1
    for (int h = h0; h < hend; ++h) {
        // 1. prefetch raw x for padded row h+7 (ht = h+3); latency hidden by conv
        float px0, px1, px2, px3, px4, px5, px6, px7, px8, px9, px10, px11;
        const bool pv = (h + 7) <= 114;
        if (pv) {
            const size_t ro = (size_t)(h + 3) * 112;
            px0  = xcol[ro];
            px1  = xcol[ro +  1*12544];
            px2  = xcol[ro +  2*12544];
            px3  = xcol[ro +  3*12544];
            px4  = xcol[ro +  4*12544];
            px5  = xcol[ro +  5*12544];
            px6  = xcol[ro +  6*12544];
            px7  = xcol[ro +  7*12544];
            px8  = xcol[ro +  8*12544];
            px9  = xcol[ro +  9*12544];
            px10 = xcol[ro + 10*12544];
            px11 = xcol[ro + 11*12544];
        } else {
            px0=px1=px2=px3=px4=px5=px6=px7=px8=px9=px10=px11=0.f;
        }

        // 2. conv: 63 taps x 12 output channels
        float a0=0.f,a1=0.f,a2=0.f,a3=0.f,a4=0.f,a5=0.f,
              a6=0.f,a7=0.f,a8=0.f,a9=0.f,a10=0.f,a11=0.f;
        TAPROW(0) TAPROW(1) TAPROW(2) TAPROW(3)
        TAPROW(4) TAPROW(5) TAPROW(6)

        // 3. store 12 output channels
        {
            const size_t so = (size_t)h * 112;
            ocol[so            ] = a0;  ocol[so +  1*12544] = a1;
            ocol[so +  2*12544 ] = a2;  ocol[so +  3*12544] = a3;
            ocol[so +  4*12544 ] = a4;  ocol[so +  5*12544] = a5;
            ocol[so +  6*12544 ] = a6;  ocol[so +  7*12544] = a7;
            ocol[so +  8*12544 ] = a8;  ocol[so +  9*12544] = a9;
            ocol[so + 10*12544 ] = a10; ocol[so + 11*12544] = a11;
        }

        // 4. shift window (pure register moves)
        COPY_ROW(0,1); COPY_ROW(1,2); COPY_ROW(2,3);
        COPY_ROW(3,4); COPY_ROW(4,5); COPY_ROW(5,6);

        // 5. mix prefetched raw row into slot 6
        MIX_ROW(6);
    }
}

extern "C" void kernel_launch(void* const* d_in, const int* in_sizes, int n_in,
                              void* d_out, int out_size, void* d_ws, size_t ws_size,
                              hipStream_t stream) {
    (void)in_sizes; (void)n_in; (void)out_size; (void)d_ws; (void)ws_size;
    const float* x  = (const float*)d_in[0];
    const float* w1 = (const float*)d_in[1];
    const float* w2 = (const float*)d_in[2];
    float* out = (float*)d_out;

    dim3 grid(128 * 2 * NCHK);   // 2048 blocks
    dim3 block(128);
    fused_shift_conv_kernel<<<grid, block, 0, stream>>>(x, w1, w2, out);
}